// Round 8
// baseline (1290.217 us; speedup 1.0000x reference)
//
#include <hip/hip_runtime.h>
#include <hip/hip_bf16.h>

typedef _Float16 f16;
typedef _Float16 half8 __attribute__((ext_vector_type(8)));
typedef float f32x4 __attribute__((ext_vector_type(4)));
typedef int i32x4 __attribute__((ext_vector_type(4)));

// B=32, S=1024, D=256, H=256, 4H=1024
// Scan: all 1024 gate cols via i8 MFMA. 64 WGs = (dir,b), 16 waves.
// Wave w owns tiles {g*16+w : g=0..3} = gate cols {g*256 + w*16..+15} -> after
// its MFMAs, lanes 0-15 hold all 4 gate preacts for h-col w*16+lane in regs;
// gates fused, no pre[] array, one barrier/step (double-buffered h).

// ---------------- prep: per-column int8 quantization of U (mfma layout) -----
// UQm uint4 index: ((dir*64 + tile)*4 + ks)*64 + kg*16 + colr
//   holds k = ks*64 + kg*16 + {0..15} (16 int8) for col = tile*16 + colr.
__global__ void prep_uq_kernel(const float* __restrict__ Uf, const float* __restrict__ Ur,
                               unsigned int* __restrict__ UQm, float* __restrict__ Uscale)
{
    int idx = blockIdx.x * 256 + threadIdx.x;   // (dir, c)
    if (idx >= 2048) return;
    int dir = idx >> 10, c = idx & 1023;
    const float* U = dir ? Ur : Uf;
    float m = 0.f;
    for (int k = 0; k < 256; ++k) m = fmaxf(m, fabsf(U[k * 1024 + c]));
    float sinv = (m > 0.f) ? 127.f / m : 0.f;
    int tile = c >> 4, colr = c & 15;
    uint4* UQm4 = (uint4*)UQm;
    for (int ks = 0; ks < 4; ++ks) {
        #pragma unroll
        for (int kg = 0; kg < 4; ++kg) {
            unsigned int w[4];
            #pragma unroll
            for (int d = 0; d < 4; ++d) {
                unsigned int wd = 0;
                #pragma unroll
                for (int e = 0; e < 4; ++e) {
                    int k = ks * 64 + kg * 16 + d * 4 + e;
                    int q = __float2int_rn(U[k * 1024 + c] * sinv);
                    wd |= ((unsigned int)(q & 0xff)) << (8 * e);
                }
                w[d] = wd;
            }
            UQm4[((size_t)((dir * 64 + tile) * 4 + ks)) * 64 + kg * 16 + colr] =
                make_uint4(w[0], w[1], w[2], w[3]);
        }
    }
    Uscale[idx] = m / (127.f * 127.f);  // U-scale * h-dequant(1/127)
}

// ---------------- projection GEMM (unchanged, proven) -----------------------
__global__ __launch_bounds__(256) void proj_gemm_kernel(
    const float* __restrict__ x, const float* __restrict__ Wf, const float* __restrict__ Wr,
    const float* __restrict__ bfw, const float* __restrict__ brw, f16* __restrict__ G)
{
    const int nt = blockIdx.x;
    const int mt = blockIdx.y;
    const int m0 = mt * 128, n0 = nt * 128;
    const int dir = n0 >> 10, nin0 = n0 & 1023;
    const float* W   = dir ? Wr : Wf;
    const float* bia = dir ? brw : bfw;
    __shared__ f16 Asm[128][40];
    __shared__ f16 Bsm[128][40];
    const int t = threadIdx.x;
    const int lane = t & 63, wave = t >> 6;
    const int wr = wave >> 1, wc = wave & 1;
    f32x4 acc[4][4] = {};
    for (int k0 = 0; k0 < 256; k0 += 32) {
        #pragma unroll
        for (int e = 0; e < 16; ++e) {
            int idx = e * 256 + t;
            int r = idx >> 5, kk = idx & 31;
            Asm[r][kk] = (f16)x[(size_t)(m0 + r) * 256 + (k0 + kk)];
        }
        #pragma unroll
        for (int e = 0; e < 16; ++e) {
            int idx = e * 256 + t;
            int col = idx & 127, kr = idx >> 7;
            Bsm[col][kr] = (f16)W[(size_t)(k0 + kr) * 1024 + (nin0 + col)];
        }
        __syncthreads();
        const int l15 = lane & 15, kb = (lane >> 4) * 8;
        half8 af[4], bfr[4];
        #pragma unroll
        for (int fr = 0; fr < 4; ++fr) af[fr]  = *(const half8*)&Asm[wr * 64 + fr * 16 + l15][kb];
        #pragma unroll
        for (int fc = 0; fc < 4; ++fc) bfr[fc] = *(const half8*)&Bsm[wc * 64 + fc * 16 + l15][kb];
        #pragma unroll
        for (int fr = 0; fr < 4; ++fr)
            #pragma unroll
            for (int fc = 0; fc < 4; ++fc)
                acc[fr][fc] = __builtin_amdgcn_mfma_f32_16x16x32_f16(af[fr], bfr[fc], acc[fr][fc], 0, 0, 0);
        __syncthreads();
    }
    const int row4 = (lane >> 4) * 4, c15 = lane & 15;
    #pragma unroll
    for (int fr = 0; fr < 4; ++fr)
        #pragma unroll
        for (int fc = 0; fc < 4; ++fc) {
            int rbase = m0 + wr * 64 + fr * 16 + row4;
            int cidx  = n0 + wc * 64 + fc * 16 + c15;
            float bv = bia[cidx & 1023];
            #pragma unroll
            for (int i = 0; i < 4; ++i)
                G[(size_t)(rbase + i) * 2048 + cidx] = (f16)(acc[fr][fc][i] + bv);
        }
}

// ---------------- scan ------------------------------------------------------
__device__ __forceinline__ float tanh_fast(float x) {
    float e = __expf(2.f * x);
    return 1.f - 2.f / (e + 1.f);
}

__global__
__attribute__((amdgpu_flat_work_group_size(1024, 1024)))
__attribute__((amdgpu_waves_per_eu(4, 4)))
void scan_kernel(
    const f16* __restrict__ G, const unsigned int* __restrict__ UQm,
    const float* __restrict__ Uscale, float* __restrict__ out)
{
    const int wg = blockIdx.x;
    const int dir = wg >> 5, b = wg & 31;
    const int tid = threadIdx.x;
    const int wave = tid >> 6, lane = tid & 63;
    const bool ep = (lane < 16);                // epilogue lanes

    __shared__ __align__(16) unsigned int hq[128];  // 2 bufs x 256B int8 h
    if (tid < 64) hq[tid] = 0u;                     // buf0 = h0 = 0

    // B-fragments: gate g of my h-cols -> tile g*16+wave. 64 regs, AGPR-ok.
    const i32x4* UQm4 = (const i32x4*)UQm;
    i32x4 uf0[4], uf1[4], uf2[4], uf3[4];
    #pragma unroll
    for (int ks = 0; ks < 4; ++ks) {
        uf0[ks] = UQm4[((size_t)((dir * 64 + ( 0 + wave)) * 4 + ks)) * 64 + lane];
        uf1[ks] = UQm4[((size_t)((dir * 64 + (16 + wave)) * 4 + ks)) * 64 + lane];
        uf2[ks] = UQm4[((size_t)((dir * 64 + (32 + wave)) * 4 + ks)) * 64 + lane];
        uf3[ks] = UQm4[((size_t)((dir * 64 + (48 + wave)) * 4 + ks)) * 64 + lane];
    }

    float usc0 = 0.f, usc1 = 0.f, usc2 = 0.f, usc3 = 0.f;
    if (ep) {
        usc0 = Uscale[dir * 1024 +   0 + wave * 16 + lane];
        usc1 = Uscale[dir * 1024 + 256 + wave * 16 + lane];
        usc2 = Uscale[dir * 1024 + 512 + wave * 16 + lane];
        usc3 = Uscale[dir * 1024 + 768 + wave * 16 + lane];
    }

    // xW state for my h-col (lanes 0-15): cols wave*16+lane + g*256
    const f16* Gg = G + (size_t)b * 1024 * 2048 + dir * 1024 + wave * 16 + lane;
    float* outp = out + (size_t)b * 1024 * 512 + dir * 256 + wave * 16 + lane;
    float xw0 = 0.f, xw1 = 0.f, xw2 = 0.f, xw3 = 0.f;
    const int s0 = dir ? 1023 : 0;
    if (ep) {
        xw0 = (float)Gg[(size_t)s0 * 2048 +   0];
        xw1 = (float)Gg[(size_t)s0 * 2048 + 256];
        xw2 = (float)Gg[(size_t)s0 * 2048 + 512];
        xw3 = (float)Gg[(size_t)s0 * 2048 + 768];
    }
    float c_state = 0.f;
    __syncthreads();

    char* hqb = (char*)hq;
    const int arow = (lane >> 4) << 4;          // A-fragment byte offset
    int p = 0;                                  // read buffer (0/1)

    for (int t = 0; t < 1024; ++t) {
        const int s  = dir ? (1023 - t) : t;
        const int tn = (t < 1023) ? (t + 1) : t;
        const int sn = dir ? (1023 - tn) : tn;

        f16 xn0, xn1, xn2, xn3;                 // prefetch next step's xW
        if (ep) {
            xn0 = Gg[(size_t)sn * 2048 +   0];
            xn1 = Gg[(size_t)sn * 2048 + 256];
            xn2 = Gg[(size_t)sn * 2048 + 512];
            xn3 = Gg[(size_t)sn * 2048 + 768];
        }

        // A = h broadcast (addr indep of lane&15); exact i32 accumulation
        i32x4 acc0 = {0,0,0,0}, acc1 = {0,0,0,0}, acc2 = {0,0,0,0}, acc3 = {0,0,0,0};
        #pragma unroll
        for (int ks = 0; ks < 4; ++ks) {
            i32x4 a = *(const i32x4*)(hqb + p * 256 + ks * 64 + arow);
            acc0 = __builtin_amdgcn_mfma_i32_16x16x64_i8(a, uf0[ks], acc0, 0, 0, 0);
            acc1 = __builtin_amdgcn_mfma_i32_16x16x64_i8(a, uf1[ks], acc1, 0, 0, 0);
            acc2 = __builtin_amdgcn_mfma_i32_16x16x64_i8(a, uf2[ks], acc2, 0, 0, 0);
            acc3 = __builtin_amdgcn_mfma_i32_16x16x64_i8(a, uf3[ks], acc3, 0, 0, 0);
        }

        if (ep) {                               // row 0 of C = h @ U
            float pi = (float)acc0[0] * usc0 + xw0;
            float pf = (float)acc1[0] * usc1 + xw1;
            float pg = (float)acc2[0] * usc2 + xw2;
            float po = (float)acc3[0] * usc3 + xw3;
            float ig = 1.f / (1.f + __expf(-pi));
            float fg = 1.f / (1.f + __expf(-pf));
            float gg = tanh_fast(pg);
            float og = 1.f / (1.f + __expf(-po));
            c_state = fg * c_state + ig * gg;
            float h = og * tanh_fast(c_state);
            outp[(size_t)s * 512] = h;
            hqb[(1 - p) * 256 + wave * 16 + lane] =
                (char)(signed char)__float2int_rn(h * 127.f);
            xw0 = (float)xn0; xw1 = (float)xn1; xw2 = (float)xn2; xw3 = (float)xn3;
        }
        // single barrier: step-t reads of buf p are before it; step-t+1
        // writes go to buf p only after it (double-buffer correctness)
        __syncthreads();
        p ^= 1;
    }
}

extern "C" void kernel_launch(void* const* d_in, const int* in_sizes, int n_in,
                              void* d_out, int out_size, void* d_ws, size_t ws_size,
                              hipStream_t stream) {
    const float* x  = (const float*)d_in[0];
    const float* Wf = (const float*)d_in[1];
    const float* Uf = (const float*)d_in[2];
    const float* bf = (const float*)d_in[3];
    const float* Wr = (const float*)d_in[4];
    const float* Ur = (const float*)d_in[5];
    const float* br = (const float*)d_in[6];
    float* out = (float*)d_out;

    char* ws = (char*)d_ws;
    unsigned int* UQm = (unsigned int*)ws;                      // 512 KB
    float* Uscale     = (float*)(ws + (size_t)512 * 1024);      // 8 KB
    f16* G            = (f16*)(ws + (size_t)1024 * 1024);       // 128 MB

    prep_uq_kernel<<<8, 256, 0, stream>>>(Uf, Ur, UQm, Uscale);
    dim3 gg(16, 256);
    proj_gemm_kernel<<<gg, 256, 0, stream>>>(x, Wf, Wr, bf, br, G);
    scan_kernel<<<64, 1024, 0, stream>>>(G, UQm, Uscale, out);
}

// Round 9
// 1081.563 us; speedup vs baseline: 1.1929x; 1.1929x over previous
//
#include <hip/hip_runtime.h>
#include <hip/hip_bf16.h>

typedef _Float16 f16;
typedef _Float16 half8 __attribute__((ext_vector_type(8)));
typedef float f32x4 __attribute__((ext_vector_type(4)));
typedef int i32x4 __attribute__((ext_vector_type(4)));

// B=32, S=1024, D=256, H=256, 4H=1024
// Scan: ALL 1024 gate cols via i8 MFMA (r6/r7-verified layout). 64 WGs =
// (dir,b), 16 waves; wave w owns tiles w*4..w*4+3 (cols w*64..w*64+63).
// Two-phase (r7): MFMA on 16 waves -> barrier -> gates on waves 0-3 (full
// 64-lane) -> barrier. r9 change: barriers drain ONLY lgkmcnt, so the gate
// waves' xW HBM prefetch (~900 cy) stays in flight across both barriers
// instead of being exposed at barrier #1 every step (r7's ~800 cy/step gap).

// ---------------- prep: per-column int8 quantization of U (mfma layout) -----
// UQm uint4 index: ((dir*64 + tile)*4 + ks)*64 + kg*16 + colr
//   holds k = ks*64 + kg*16 + {0..15} (16 int8) for col = tile*16 + colr.
__global__ void prep_uq_kernel(const float* __restrict__ Uf, const float* __restrict__ Ur,
                               unsigned int* __restrict__ UQm, float* __restrict__ Uscale)
{
    int idx = blockIdx.x * 256 + threadIdx.x;   // (dir, c)
    if (idx >= 2048) return;
    int dir = idx >> 10, c = idx & 1023;
    const float* U = dir ? Ur : Uf;
    float m = 0.f;
    for (int k = 0; k < 256; ++k) m = fmaxf(m, fabsf(U[k * 1024 + c]));
    float sinv = (m > 0.f) ? 127.f / m : 0.f;
    int tile = c >> 4, colr = c & 15;
    uint4* UQm4 = (uint4*)UQm;
    for (int ks = 0; ks < 4; ++ks) {
        #pragma unroll
        for (int kg = 0; kg < 4; ++kg) {
            unsigned int w[4];
            #pragma unroll
            for (int d = 0; d < 4; ++d) {
                unsigned int wd = 0;
                #pragma unroll
                for (int e = 0; e < 4; ++e) {
                    int k = ks * 64 + kg * 16 + d * 4 + e;
                    int q = __float2int_rn(U[k * 1024 + c] * sinv);
                    wd |= ((unsigned int)(q & 0xff)) << (8 * e);
                }
                w[d] = wd;
            }
            UQm4[((size_t)((dir * 64 + tile) * 4 + ks)) * 64 + kg * 16 + colr] =
                make_uint4(w[0], w[1], w[2], w[3]);
        }
    }
    Uscale[idx] = m / (127.f * 127.f);  // U-scale * h-dequant(1/127)
}

// ---------------- projection GEMM (unchanged, proven) -----------------------
__global__ __launch_bounds__(256) void proj_gemm_kernel(
    const float* __restrict__ x, const float* __restrict__ Wf, const float* __restrict__ Wr,
    const float* __restrict__ bfw, const float* __restrict__ brw, f16* __restrict__ G)
{
    const int nt = blockIdx.x;
    const int mt = blockIdx.y;
    const int m0 = mt * 128, n0 = nt * 128;
    const int dir = n0 >> 10, nin0 = n0 & 1023;
    const float* W   = dir ? Wr : Wf;
    const float* bia = dir ? brw : bfw;
    __shared__ f16 Asm[128][40];
    __shared__ f16 Bsm[128][40];
    const int t = threadIdx.x;
    const int lane = t & 63, wave = t >> 6;
    const int wr = wave >> 1, wc = wave & 1;
    f32x4 acc[4][4] = {};
    for (int k0 = 0; k0 < 256; k0 += 32) {
        #pragma unroll
        for (int e = 0; e < 16; ++e) {
            int idx = e * 256 + t;
            int r = idx >> 5, kk = idx & 31;
            Asm[r][kk] = (f16)x[(size_t)(m0 + r) * 256 + (k0 + kk)];
        }
        #pragma unroll
        for (int e = 0; e < 16; ++e) {
            int idx = e * 256 + t;
            int col = idx & 127, kr = idx >> 7;
            Bsm[col][kr] = (f16)W[(size_t)(k0 + kr) * 1024 + (nin0 + col)];
        }
        __syncthreads();
        const int l15 = lane & 15, kb = (lane >> 4) * 8;
        half8 af[4], bfr[4];
        #pragma unroll
        for (int fr = 0; fr < 4; ++fr) af[fr]  = *(const half8*)&Asm[wr * 64 + fr * 16 + l15][kb];
        #pragma unroll
        for (int fc = 0; fc < 4; ++fc) bfr[fc] = *(const half8*)&Bsm[wc * 64 + fc * 16 + l15][kb];
        #pragma unroll
        for (int fr = 0; fr < 4; ++fr)
            #pragma unroll
            for (int fc = 0; fc < 4; ++fc)
                acc[fr][fc] = __builtin_amdgcn_mfma_f32_16x16x32_f16(af[fr], bfr[fc], acc[fr][fc], 0, 0, 0);
        __syncthreads();
    }
    const int row4 = (lane >> 4) * 4, c15 = lane & 15;
    #pragma unroll
    for (int fr = 0; fr < 4; ++fr)
        #pragma unroll
        for (int fc = 0; fc < 4; ++fc) {
            int rbase = m0 + wr * 64 + fr * 16 + row4;
            int cidx  = n0 + wc * 64 + fc * 16 + c15;
            float bv = bia[cidx & 1023];
            #pragma unroll
            for (int i = 0; i < 4; ++i)
                G[(size_t)(rbase + i) * 2048 + cidx] = (f16)(acc[fr][fc][i] + bv);
        }
}

// ---------------- scan ------------------------------------------------------
__device__ __forceinline__ float tanh_fast(float x) {
    float e = __expf(2.f * x);
    return 1.f - 2.f / (e + 1.f);
}

// Barrier that drains ONLY lgkmcnt (LDS), leaving global loads in flight.
// sched_barrier(0) per guide rule #18 (stop hoisting past the asm waitcnt).
#define LGKM_BARRIER() do { \
    asm volatile("s_waitcnt lgkmcnt(0)\n\ts_barrier" ::: "memory"); \
    __builtin_amdgcn_sched_barrier(0); \
} while (0)

__global__
__attribute__((amdgpu_flat_work_group_size(1024, 1024)))
__attribute__((amdgpu_waves_per_eu(4, 4)))
void scan_kernel(
    const f16* __restrict__ G, const unsigned int* __restrict__ UQm,
    const float* __restrict__ Uscale, float* __restrict__ out)
{
    const int wg = blockIdx.x;
    const int dir = wg >> 5, b = wg & 31;
    const int tid = threadIdx.x;
    const int wave = tid >> 6, lane = tid & 63;
    const bool is_gate = (tid < 256);           // waves 0-3 (one per SIMD)
    const int gc = tid & 255;

    __shared__ __align__(16) unsigned int hq[64];   // h int8[256]
    __shared__ float pre[1024];                     // scaled recurrent term

    if (tid < 64) hq[tid] = 0u;

    // B-fragments: 4 tiles x 4 K-steps, i32x4 each = 64 regs (AGPR-resident;
    // MFMA reads AGPRs natively)
    const i32x4* UQm4 = (const i32x4*)UQm;
    i32x4 uf[4][4];
    #pragma unroll
    for (int tau = 0; tau < 4; ++tau)
        #pragma unroll
        for (int ks = 0; ks < 4; ++ks)
            uf[tau][ks] = UQm4[((size_t)((dir * 64 + wave * 4 + tau) * 4 + ks)) * 64 + lane];

    float usc[4] = {0.f, 0.f, 0.f, 0.f};
    if (lane < 16) {
        #pragma unroll
        for (int tau = 0; tau < 4; ++tau)
            usc[tau] = Uscale[dir * 1024 + wave * 64 + tau * 16 + lane];
    }

    // gate-thread state
    const f16* Grow = G + (size_t)b * 1024 * 2048 + dir * 1024 + gc;
    float* outp = out + (size_t)b * 1024 * 512 + dir * 256 + gc;
    float xwc0 = 0.f, xwc1 = 0.f, xwc2 = 0.f, xwc3 = 0.f;
    float c_state = 0.f;
    const int s0 = dir ? 1023 : 0;
    if (is_gate) {
        xwc0 = (float)Grow[(size_t)s0 * 2048 + 0];
        xwc1 = (float)Grow[(size_t)s0 * 2048 + 256];
        xwc2 = (float)Grow[(size_t)s0 * 2048 + 512];
        xwc3 = (float)Grow[(size_t)s0 * 2048 + 768];
    }
    __syncthreads();

    const char* hqb = (const char*)hq;
    const int arow = (lane >> 4) << 4;          // A-fragment byte offset in h

    for (int t = 0; t < 1024; ++t) {
        const int s  = dir ? (1023 - t) : t;
        const int tn = (t < 1023) ? (t + 1) : t;
        const int sn = dir ? (1023 - tn) : tn;

        f16 xn0, xn1, xn2, xn3;
        if (is_gate) {                          // prefetch next step's xW
            xn0 = Grow[(size_t)sn * 2048 + 0];
            xn1 = Grow[(size_t)sn * 2048 + 256];
            xn2 = Grow[(size_t)sn * 2048 + 512];
            xn3 = Grow[(size_t)sn * 2048 + 768];
        }

        // pre[wave*64 + tau*16 + col] = (h @ U)[col] * usc   (exact i32 accum)
        // A = h replicated across the 16 rows (addr indep of lane&15), so
        // every C row holds the result; lanes 0-15 reg 0 = row 0.
        i32x4 acc0 = {0,0,0,0}, acc1 = {0,0,0,0}, acc2 = {0,0,0,0}, acc3 = {0,0,0,0};
        #pragma unroll
        for (int ks = 0; ks < 4; ++ks) {
            i32x4 a = *(const i32x4*)(hqb + ks * 64 + arow);
            acc0 = __builtin_amdgcn_mfma_i32_16x16x64_i8(a, uf[0][ks], acc0, 0, 0, 0);
            acc1 = __builtin_amdgcn_mfma_i32_16x16x64_i8(a, uf[1][ks], acc1, 0, 0, 0);
            acc2 = __builtin_amdgcn_mfma_i32_16x16x64_i8(a, uf[2][ks], acc2, 0, 0, 0);
            acc3 = __builtin_amdgcn_mfma_i32_16x16x64_i8(a, uf[3][ks], acc3, 0, 0, 0);
        }
        if (lane < 16) {
            pre[wave * 64 +  0 + lane] = (float)acc0[0] * usc[0];
            pre[wave * 64 + 16 + lane] = (float)acc1[0] * usc[1];
            pre[wave * 64 + 32 + lane] = (float)acc2[0] * usc[2];
            pre[wave * 64 + 48 + lane] = (float)acc3[0] * usc[3];
        }
        // barrier #1: pre visible; hq may be overwritten after (MFMA operands
        // already consumed at issue). Global xW loads stay in flight.
        LGKM_BARRIER();

        if (is_gate) {
            float pi = pre[gc      ] + xwc0;
            float pf = pre[gc + 256] + xwc1;
            float pg = pre[gc + 512] + xwc2;
            float po = pre[gc + 768] + xwc3;
            float ig = 1.f / (1.f + __expf(-pi));
            float fg = 1.f / (1.f + __expf(-pf));
            float gg = tanh_fast(pg);
            float og = 1.f / (1.f + __expf(-po));
            c_state = fg * c_state + ig * gg;
            float h = og * tanh_fast(c_state);
            outp[(size_t)s * 512] = h;
            ((signed char*)hq)[gc] = (signed char)__float2int_rn(h * 127.f);
            xwc0 = (float)xn0; xwc1 = (float)xn1; xwc2 = (float)xn2; xwc3 = (float)xn3;
        }
        // barrier #2: new hq visible for next step's MFMA reads.
        LGKM_BARRIER();
    }
}

extern "C" void kernel_launch(void* const* d_in, const int* in_sizes, int n_in,
                              void* d_out, int out_size, void* d_ws, size_t ws_size,
                              hipStream_t stream) {
    const float* x  = (const float*)d_in[0];
    const float* Wf = (const float*)d_in[1];
    const float* Uf = (const float*)d_in[2];
    const float* bf = (const float*)d_in[3];
    const float* Wr = (const float*)d_in[4];
    const float* Ur = (const float*)d_in[5];
    const float* br = (const float*)d_in[6];
    float* out = (float*)d_out;

    char* ws = (char*)d_ws;
    unsigned int* UQm = (unsigned int*)ws;                      // 512 KB
    float* Uscale     = (float*)(ws + (size_t)512 * 1024);      // 8 KB
    f16* G            = (f16*)(ws + (size_t)1024 * 1024);       // 128 MB

    prep_uq_kernel<<<8, 256, 0, stream>>>(Uf, Ur, UQm, Uscale);
    dim3 gg(16, 256);
    proj_gemm_kernel<<<gg, 256, 0, stream>>>(x, Wf, Wr, bf, br, G);
    scan_kernel<<<64, 1024, 0, stream>>>(G, UQm, Uscale, out);
}

// Round 10
// 1080.159 us; speedup vs baseline: 1.1945x; 1.0013x over previous
//
#include <hip/hip_runtime.h>
#include <hip/hip_bf16.h>

typedef _Float16 f16;
typedef _Float16 half8 __attribute__((ext_vector_type(8)));
typedef float f32x4 __attribute__((ext_vector_type(4)));
typedef int i32x4 __attribute__((ext_vector_type(4)));

// B=32, S=1024, D=256, H=256, 4H=1024
// Scan r10: i8-MFMA recurrent matmul + quad-gate epilogue, 1 barrier/step.
// Wave w owns tiles {g*16+w} (all 4 gates of h-cols w*16..w*16+15).
// Lane l = gate (l&3) of h-col w*16+(l>>2); quads combine via DPP quad_perm.

// ---------------- prep: per-column int8 quantization of U (mfma layout) -----
// UQm uint4 index: ((dir*64 + tile)*4 + ks)*64 + kg*16 + colr
//   holds k = ks*64 + kg*16 + {0..15} (16 int8) for col = tile*16 + colr.
__global__ void prep_uq_kernel(const float* __restrict__ Uf, const float* __restrict__ Ur,
                               unsigned int* __restrict__ UQm, float* __restrict__ Uscale)
{
    int idx = blockIdx.x * 256 + threadIdx.x;   // (dir, c)
    if (idx >= 2048) return;
    int dir = idx >> 10, c = idx & 1023;
    const float* U = dir ? Ur : Uf;
    float m = 0.f;
    for (int k = 0; k < 256; ++k) m = fmaxf(m, fabsf(U[k * 1024 + c]));
    float sinv = (m > 0.f) ? 127.f / m : 0.f;
    int tile = c >> 4, colr = c & 15;
    uint4* UQm4 = (uint4*)UQm;
    for (int ks = 0; ks < 4; ++ks) {
        #pragma unroll
        for (int kg = 0; kg < 4; ++kg) {
            unsigned int w[4];
            #pragma unroll
            for (int d = 0; d < 4; ++d) {
                unsigned int wd = 0;
                #pragma unroll
                for (int e = 0; e < 4; ++e) {
                    int k = ks * 64 + kg * 16 + d * 4 + e;
                    int q = __float2int_rn(U[k * 1024 + c] * sinv);
                    wd |= ((unsigned int)(q & 0xff)) << (8 * e);
                }
                w[d] = wd;
            }
            UQm4[((size_t)((dir * 64 + tile) * 4 + ks)) * 64 + kg * 16 + colr] =
                make_uint4(w[0], w[1], w[2], w[3]);
        }
    }
    Uscale[idx] = m / (127.f * 127.f);  // U-scale * h-dequant(1/127)
}

// ---------------- projection GEMM (unchanged, proven) -----------------------
__global__ __launch_bounds__(256) void proj_gemm_kernel(
    const float* __restrict__ x, const float* __restrict__ Wf, const float* __restrict__ Wr,
    const float* __restrict__ bfw, const float* __restrict__ brw, f16* __restrict__ G)
{
    const int nt = blockIdx.x;
    const int mt = blockIdx.y;
    const int m0 = mt * 128, n0 = nt * 128;
    const int dir = n0 >> 10, nin0 = n0 & 1023;
    const float* W   = dir ? Wr : Wf;
    const float* bia = dir ? brw : bfw;
    __shared__ f16 Asm[128][40];
    __shared__ f16 Bsm[128][40];
    const int t = threadIdx.x;
    const int lane = t & 63, wave = t >> 6;
    const int wr = wave >> 1, wc = wave & 1;
    f32x4 acc[4][4] = {};
    for (int k0 = 0; k0 < 256; k0 += 32) {
        #pragma unroll
        for (int e = 0; e < 16; ++e) {
            int idx = e * 256 + t;
            int r = idx >> 5, kk = idx & 31;
            Asm[r][kk] = (f16)x[(size_t)(m0 + r) * 256 + (k0 + kk)];
        }
        #pragma unroll
        for (int e = 0; e < 16; ++e) {
            int idx = e * 256 + t;
            int col = idx & 127, kr = idx >> 7;
            Bsm[col][kr] = (f16)W[(size_t)(k0 + kr) * 1024 + (nin0 + col)];
        }
        __syncthreads();
        const int l15 = lane & 15, kb = (lane >> 4) * 8;
        half8 af[4], bfr[4];
        #pragma unroll
        for (int fr = 0; fr < 4; ++fr) af[fr]  = *(const half8*)&Asm[wr * 64 + fr * 16 + l15][kb];
        #pragma unroll
        for (int fc = 0; fc < 4; ++fc) bfr[fc] = *(const half8*)&Bsm[wc * 64 + fc * 16 + l15][kb];
        #pragma unroll
        for (int fr = 0; fr < 4; ++fr)
            #pragma unroll
            for (int fc = 0; fc < 4; ++fc)
                acc[fr][fc] = __builtin_amdgcn_mfma_f32_16x16x32_f16(af[fr], bfr[fc], acc[fr][fc], 0, 0, 0);
        __syncthreads();
    }
    const int row4 = (lane >> 4) * 4, c15 = lane & 15;
    #pragma unroll
    for (int fr = 0; fr < 4; ++fr)
        #pragma unroll
        for (int fc = 0; fc < 4; ++fc) {
            int rbase = m0 + wr * 64 + fr * 16 + row4;
            int cidx  = n0 + wc * 64 + fc * 16 + c15;
            float bv = bia[cidx & 1023];
            #pragma unroll
            for (int i = 0; i < 4; ++i)
                G[(size_t)(rbase + i) * 2048 + cidx] = (f16)(acc[fr][fc][i] + bv);
        }
}

// ---------------- scan ------------------------------------------------------
template<int PAT>
__device__ __forceinline__ float qb(float v) {   // quad_perm broadcast
    return __int_as_float(__builtin_amdgcn_mov_dpp(__float_as_int(v), PAT, 0xF, 0xF, true));
}

#define LGKM_BARRIER() do { \
    asm volatile("s_waitcnt lgkmcnt(0)\n\ts_barrier" ::: "memory"); \
    __builtin_amdgcn_sched_barrier(0); \
} while (0)

__global__
__attribute__((amdgpu_flat_work_group_size(1024, 1024)))
__attribute__((amdgpu_waves_per_eu(4, 4)))
void scan_kernel(
    const f16* __restrict__ G, const unsigned int* __restrict__ UQm,
    const float* __restrict__ Uscale, float* __restrict__ out)
{
    const int wg = blockIdx.x;
    const int dir = wg >> 5, b = wg & 31;
    const int tid = threadIdx.x;
    const int wave = tid >> 6, lane = tid & 63;
    const int colq = lane >> 2, gate = lane & 3;    // lane -> (col, gate)
    const int mycol = wave * 16 + colq;

    __shared__ __align__(16) unsigned int hq[128];  // 2 bufs x 256B int8 h
    __shared__ __align__(16) int scr[1024];         // per-wave 16 cols x 4 gates

    if (tid < 64) hq[tid] = 0u;                     // buf0 = h0 = 0

    // B-fragments: gate g of my h-cols -> tile g*16+wave (64 regs, AGPR-ok)
    const i32x4* UQm4 = (const i32x4*)UQm;
    i32x4 uf0[4], uf1[4], uf2[4], uf3[4];
    #pragma unroll
    for (int ks = 0; ks < 4; ++ks) {
        uf0[ks] = UQm4[((size_t)((dir * 64 + ( 0 + wave)) * 4 + ks)) * 64 + lane];
        uf1[ks] = UQm4[((size_t)((dir * 64 + (16 + wave)) * 4 + ks)) * 64 + lane];
        uf2[ks] = UQm4[((size_t)((dir * 64 + (32 + wave)) * 4 + ks)) * 64 + lane];
        uf3[ks] = UQm4[((size_t)((dir * 64 + (48 + wave)) * 4 + ks)) * 64 + lane];
    }

    // per-lane dequant scale for (gate, mycol)
    const float uscl = Uscale[dir * 1024 + gate * 256 + mycol];

    // per-lane xW stream: G[s][dir*1024 + gate*256 + mycol]
    const f16* Gl = G + (size_t)b * 1024 * 2048 + dir * 1024 + gate * 256 + mycol;
    float* outp = out + (size_t)b * 1024 * 512 + dir * 256 + mycol;

    const int s0 = dir ? 1023 : 0;
    float xw = (float)Gl[(size_t)s0 * 2048];
    float c_state = 0.f;                            // replicated per quad
    __syncthreads();

    const char* hqb = (const char*)hq;
    signed char* hqw = (signed char*)hq;
    int* scrw = scr + wave * 64;
    const int arow = (lane >> 4) << 4;              // A-frag byte offset
    int p = 0;

    for (int t = 0; t < 1024; ++t) {
        const int s  = dir ? (1023 - t) : t;
        const int tn = (t < 1023) ? (t + 1) : t;
        const int sn = dir ? (1023 - tn) : tn;
        f16 xn = Gl[(size_t)sn * 2048];             // prefetch next xW

        // h @ U, exact i32: A = h broadcast across rows; row 0 = result
        i32x4 acc0 = {0,0,0,0}, acc1 = {0,0,0,0}, acc2 = {0,0,0,0}, acc3 = {0,0,0,0};
        #pragma unroll
        for (int ks = 0; ks < 4; ++ks) {
            i32x4 a = *(const i32x4*)(hqb + p * 256 + ks * 64 + arow);
            acc0 = __builtin_amdgcn_mfma_i32_16x16x64_i8(a, uf0[ks], acc0, 0, 0, 0);
            acc1 = __builtin_amdgcn_mfma_i32_16x16x64_i8(a, uf1[ks], acc1, 0, 0, 0);
            acc2 = __builtin_amdgcn_mfma_i32_16x16x64_i8(a, uf2[ks], acc2, 0, 0, 0);
            acc3 = __builtin_amdgcn_mfma_i32_16x16x64_i8(a, uf3[ks], acc3, 0, 0, 0);
        }

        // lanes 0-15 (=col j): dump raw i32 {i,f,g,o} as one b128 (wave-local)
        if (lane < 16) {
            i32x4 pv; pv[0] = acc0[0]; pv[1] = acc1[0]; pv[2] = acc2[0]; pv[3] = acc3[0];
            *(i32x4*)(scrw + lane * 4) = pv;
        }
        asm volatile("s_waitcnt lgkmcnt(0)" ::: "memory");   // wave-local RAW
        __builtin_amdgcn_sched_barrier(0);

        // every lane: one (col, gate) value
        int iv = scrw[colq * 4 + gate];
        float pre = (float)iv * uscl + xw;
        // unified nonlinearity: gate 2 -> tanh, else sigmoid
        float a2 = (gate == 2) ? (pre + pre) : -pre;
        float E  = __expf(a2);
        float r  = __fdividef(1.f, E + 1.f);
        float v  = (gate == 2) ? (1.f - 2.f * r) : r;
        // quad combine: b0=sig_i, b1=sig_f, b2=tanh_g, b3=sig_o
        float b0 = qb<0x00>(v), b1 = qb<0x55>(v), b2 = qb<0xAA>(v), b3 = qb<0xFF>(v);
        c_state = b1 * c_state + b0 * b2;
        float e2 = __expf(c_state + c_state);
        float th = 1.f - __fdividef(2.f, e2 + 1.f);
        float h  = b3 * th;

        if (gate == 0) outp[(size_t)s * 512] = h;
        if (gate == 1) hqw[(p ^ 1) * 256 + mycol] = (signed char)__float2int_rn(h * 127.f);

        LGKM_BARRIER();                             // new h visible to all
        p ^= 1;
        xw = (float)xn;
    }
}

extern "C" void kernel_launch(void* const* d_in, const int* in_sizes, int n_in,
                              void* d_out, int out_size, void* d_ws, size_t ws_size,
                              hipStream_t stream) {
    const float* x  = (const float*)d_in[0];
    const float* Wf = (const float*)d_in[1];
    const float* Uf = (const float*)d_in[2];
    const float* bf = (const float*)d_in[3];
    const float* Wr = (const float*)d_in[4];
    const float* Ur = (const float*)d_in[5];
    const float* br = (const float*)d_in[6];
    float* out = (float*)d_out;

    char* ws = (char*)d_ws;
    unsigned int* UQm = (unsigned int*)ws;                      // 512 KB
    float* Uscale     = (float*)(ws + (size_t)512 * 1024);      // 8 KB
    f16* G            = (f16*)(ws + (size_t)1024 * 1024);       // 128 MB

    prep_uq_kernel<<<8, 256, 0, stream>>>(Uf, Ur, UQm, Uscale);
    dim3 gg(16, 256);
    proj_gemm_kernel<<<gg, 256, 0, stream>>>(x, Wf, Wr, bf, br, G);
    scan_kernel<<<64, 1024, 0, stream>>>(G, UQm, Uscale, out);
}